// Round 8
// baseline (356.685 us; speedup 1.0000x reference)
//
#include <hip/hip_runtime.h>
#include <math.h>

#define N_NODESC 50000
#define NPAD 50048              // 1564 * 32
#define N_EDGESC 800000
#define N_GRAPHSC 64
#define IN_DIMC 128
#define HIDC 256
#define N_LAYERSC 4
#define EPSV 1e-12f

#define NBUCK 196               // buckets of 256 nodes
#define EPB 4096
#define NBLK1 196               // ceil(800000/4096)
#define WCONV_BLKS 2176         // 557056 / 256
#define PBUCK 12288             // padded slab entries per bucket (pad-16)
#define ZROW 50000              // dedicated zero row in xq (egemm writes 0)

typedef __attribute__((ext_vector_type(8))) short short8;
typedef __attribute__((ext_vector_type(4))) float floatx4;
typedef __attribute__((ext_vector_type(2))) float floatx2;

__device__ __forceinline__ unsigned short f2b(float f) {
    union { float f; unsigned u; } v; v.f = f;
    unsigned r = v.u + 0x7FFFu + ((v.u >> 16) & 1u);
    return (unsigned short)(r >> 16);
}
__device__ __forceinline__ unsigned pkb(float a, float b) {
    return (unsigned)f2b(a) | ((unsigned)f2b(b) << 16);
}
__device__ __forceinline__ unsigned char f2q(float v) {
    return (unsigned char)(__builtin_amdgcn_cvt_pk_fp8_f32(v, v, 0, false) & 0xFF);
}
__device__ __forceinline__ float q2f(unsigned u) {
    floatx2 t = __builtin_amdgcn_cvt_pk_f32_fp8(u, false);
    return t.x;   // converts byte 0
}
__device__ __forceinline__ unsigned pk4q(float a, float b, float c, float d) {
    unsigned lo = (unsigned)__builtin_amdgcn_cvt_pk_fp8_f32(a, b, 0, false) & 0xFFFFu;
    unsigned hi = (unsigned)__builtin_amdgcn_cvt_pk_fp8_f32(c, d, 0, false) << 16;
    return lo | hi;
}
__device__ __forceinline__ void ldscp16(const void* g, void* l) {
    __builtin_amdgcn_global_load_lds(
        (const __attribute__((address_space(1))) unsigned int*)g,
        (__attribute__((address_space(3))) unsigned int*)l, 16, 0, 0);
}

// ---------------- merged: weight convert | graph bounds | bucket count ----------------
__global__ __launch_bounds__(256) void k_pre1(const float* __restrict__ Wemb,
        const float* __restrict__ Ws, unsigned short* __restrict__ wsw,
        unsigned char* __restrict__ wq, const int* __restrict__ gid,
        int* __restrict__ gstart, const int* __restrict__ dst,
        int* __restrict__ gbcnt) {
    __shared__ int bc[256];
    int b = blockIdx.x;
    int t = threadIdx.x;
    if (b < WCONV_BLKS) {
        int idx = b * 256 + t;
        const int EMB = IN_DIMC * HIDC;           // 32768
        const int LYR = 2 * HIDC * HIDC;          // 131072
        if (idx < EMB) {
            int k = idx >> 8, n = idx & 255;
            int off = (((k >> 5) * 16 + (n >> 4)) * 64 + ((((k >> 3) & 3) << 4) | (n & 15))) * 8 + (k & 7);
            wsw[off] = f2b(Wemb[idx]);
        } else if (idx < EMB + N_LAYERSC * LYR) {
            int r = idx - EMB;
            int l = r >> 17;
            int r2 = r & (LYR - 1);
            int k = r2 >> 8, n = r2 & 255;
            int off = (((k >> 5) * 16 + (n >> 4)) * 64 + ((((k >> 3) & 3) << 4) | (n & 15))) * 8 + (k & 7);
            wq[(size_t)l * LYR + off] = f2q(Ws[r]);
        }
    } else if (b == WCONV_BLKS) {
        int g = t;
        if (g <= N_GRAPHSC) {
            int lo = 0, hi = N_NODESC;
            while (lo < hi) {
                int mid = (lo + hi) >> 1;
                if (gid[mid] < g) lo = mid + 1; else hi = mid;
            }
            gstart[g] = lo;
        }
    } else {
        bc[t] = 0;
        __syncthreads();
        int e0 = (b - WCONV_BLKS - 1) * EPB;
        for (int i = t; i < EPB; i += 256) {
            int e = e0 + i;
            if (e < N_EDGESC) atomicAdd(&bc[dst[e] >> 8], 1);
        }
        __syncthreads();
        if (t < NBUCK && bc[t] > 0) atomicAdd(&gbcnt[t], bc[t]);
    }
}

__global__ __launch_bounds__(256) void k_bscan(const int* __restrict__ gbcnt,
        int* __restrict__ boffB, int* __restrict__ gcurB) {
    __shared__ int s[256];
    int t = threadIdx.x;
    int v = (t < NBUCK) ? gbcnt[t] : 0;
    s[t] = v;
    __syncthreads();
    for (int d = 1; d < 256; d <<= 1) {
        int u = (t >= d) ? s[t - d] : 0;
        __syncthreads();
        s[t] += u;
        __syncthreads();
    }
    if (t < NBUCK) {
        int excl = s[t] - v;
        boffB[t] = excl;
        gcurB[t] = excl;
    }
    if (t == 0) boffB[NBUCK] = N_EDGESC;
}

// ---------------- merged: bucket scatter | embed GEMM (independent roles) ----------------
__global__ __launch_bounds__(256, 4) void k_scat_egemm(const int* __restrict__ src,
        const int* __restrict__ dst, int* __restrict__ gcurB,
        unsigned* __restrict__ ebpack, const float* __restrict__ h,
        const unsigned short* __restrict__ wsw, const float* __restrict__ bias,
        unsigned char* __restrict__ xq) {
    __shared__ int bc[256];
    __shared__ int cur[256];
    if (blockIdx.x < NBLK1) {
        int t = threadIdx.x;
        bc[t] = 0;
        __syncthreads();
        int e0 = blockIdx.x * EPB;
        for (int i = t; i < EPB; i += 256) {
            int e = e0 + i;
            if (e < N_EDGESC) atomicAdd(&bc[dst[e] >> 8], 1);
        }
        __syncthreads();
        if (t < NBUCK)
            cur[t] = (bc[t] > 0) ? atomicAdd(&gcurB[t], bc[t]) : 0;
        __syncthreads();
        for (int i = t; i < EPB; i += 256) {
            int e = e0 + i;
            if (e < N_EDGESC) {
                int d = dst[e];
                int b = d >> 8;
                int pos = atomicAdd(&cur[b], 1);
                ebpack[pos] = (unsigned)src[e] | ((unsigned)(d & 255) << 16);
            }
        }
        return;
    }
    // ---- embed GEMM role ----
    int tid = threadIdx.x;
    int wn = tid >> 6;
    int lane = tid & 63;
    int quad = lane >> 4;
    int l15 = lane & 15;
    int row0 = (blockIdx.x - NBLK1) * 32;

    floatx4 acc[2][4];
    #pragma unroll
    for (int mt = 0; mt < 2; mt++)
        #pragma unroll
        for (int n = 0; n < 4; n++)
            acc[mt][n] = (floatx4){0.f, 0.f, 0.f, 0.f};

    int r0 = row0 + l15;
    int r1 = row0 + 16 + l15;
    bool ok0 = r0 < N_NODESC, ok1 = r1 < N_NODESC;
    const float* h0 = h + (size_t)r0 * IN_DIMC + quad * 8;
    const float* h1 = h + (size_t)r1 * IN_DIMC + quad * 8;
    const unsigned short* bp = wsw + ((size_t)(wn * 4) * 64 + lane) * 8;

    #pragma unroll
    for (int ks = 0; ks < 4; ks++) {
        float4 f00 = ok0 ? *(const float4*)(h0 + ks * 32)     : (float4){0,0,0,0};
        float4 f01 = ok0 ? *(const float4*)(h0 + ks * 32 + 4) : (float4){0,0,0,0};
        float4 f10 = ok1 ? *(const float4*)(h1 + ks * 32)     : (float4){0,0,0,0};
        float4 f11 = ok1 ? *(const float4*)(h1 + ks * 32 + 4) : (float4){0,0,0,0};
        short8 afr[2], bfr[4];
        uint4 av;
        av.x = pkb(f00.x, f00.y); av.y = pkb(f00.z, f00.w);
        av.z = pkb(f01.x, f01.y); av.w = pkb(f01.z, f01.w);
        afr[0] = *(short8*)&av;
        av.x = pkb(f10.x, f10.y); av.y = pkb(f10.z, f10.w);
        av.z = pkb(f11.x, f11.y); av.w = pkb(f11.z, f11.w);
        afr[1] = *(short8*)&av;
        const unsigned short* wp = bp + (size_t)ks * 8192;
        #pragma unroll
        for (int n = 0; n < 4; n++)
            bfr[n] = *(const short8*)(wp + n * 512);
        #pragma unroll
        for (int mt = 0; mt < 2; mt++)
            #pragma unroll
            for (int n = 0; n < 4; n++)
                acc[mt][n] = __builtin_amdgcn_mfma_f32_16x16x32_bf16(
                    afr[mt], bfr[n], acc[mt][n], 0, 0, 0);
    }

    float bv[4];
    #pragma unroll
    for (int n = 0; n < 4; n++) bv[n] = bias[wn * 64 + n * 16 + l15];
    #pragma unroll
    for (int mt = 0; mt < 2; mt++) {
        #pragma unroll
        for (int r = 0; r < 4; r++) {
            int row = row0 + mt * 16 + quad * 4 + r;
            #pragma unroll
            for (int n = 0; n < 4; n++) {
                int col = wn * 64 + n * 16 + l15;
                // pad rows (incl. ZROW) written as 0 so gather padding adds nothing
                float v = acc[mt][n][r] + bv[n];
                xq[(size_t)row * HIDC + col] = (row < N_NODESC) ? f2q(v) : (unsigned char)0;
            }
        }
    }
}

// ---------------- CSR build with 16-padded per-node lists (fixed slab/bucket) ----------------
// Pad entries -> ZROW (zero row, cache-hot); true degree in ndeg.
__global__ __launch_bounds__(256) void k_bbuild(const unsigned* __restrict__ ebpack,
        const int* __restrict__ boffB, int* __restrict__ offs,
        int* __restrict__ ndeg, unsigned short* __restrict__ esrc) {
    __shared__ int deg[256];
    __shared__ int lofs[256];
    __shared__ unsigned short img[PBUCK];     // 24 KB
    int b = blockIdx.x;
    int t = threadIdx.x;
    int bbase = boffB[b];
    int cnt = boffB[b + 1] - bbase;
    deg[t] = 0;
    __syncthreads();
    for (int i = t; i < cnt; i += 256)
        atomicAdd(&deg[ebpack[bbase + i] >> 16], 1);
    __syncthreads();
    int d = deg[t];
    int pd = (d + 15) & ~15;                  // pad each list to multiple of 16
    lofs[t] = pd;
    __syncthreads();
    for (int s = 1; s < 256; s <<= 1) {
        int u = (t >= s) ? lofs[t - s] : 0;
        __syncthreads();
        lofs[t] += u;
        __syncthreads();
    }
    int pexcl = lofs[t] - pd;
    int node = b * 256 + t;
    int S = b * PBUCK;
    if (node < N_NODESC) {
        offs[node] = S + pexcl;
        ndeg[node] = d;
    }
    int ptot = lofs[255];
    for (int i = t; i < ptot; i += 256) img[i] = (unsigned short)ZROW;
    deg[t] = pexcl;                           // scatter cursor
    __syncthreads();
    for (int i = t; i < cnt; i += 256) {
        unsigned p = ebpack[bbase + i];
        int pos = atomicAdd(&deg[p >> 16], 1);
        img[pos] = (unsigned short)(p & 0xFFFF);
    }
    __syncthreads();
    for (int i = t; i < ptot; i += 256)
        esrc[S + i] = img[i];
}

// ---------------- per-node mean aggregation: 32 lanes x 8B, 16-deep load pipeline ----------------
// 16 row-loads in flight per batch (2x R6's MLP); lists 16-padded -> no tails.
__global__ __launch_bounds__(256, 8) void k_aggregate(const unsigned char* __restrict__ xq,
        const int* __restrict__ offs, const int* __restrict__ ndeg,
        const unsigned short* __restrict__ esrc, unsigned char* __restrict__ cq) {
    int gidx = blockIdx.x * 256 + threadIdx.x;
    int node = gidx >> 5;                     // grid exact: 6250 blocks * 8 nodes
    int lane = threadIdx.x & 31;
    int beg = offs[node];
    int dn = ndeg[node];
    int pd = (dn + 15) & ~15;
    int end = beg + pd;
    float a[8];
    #pragma unroll
    for (int j = 0; j < 8; j++) a[j] = 0.f;
    size_t loff = (size_t)lane * 8;
    #define ACC8(v) do { \
        floatx2 t0 = __builtin_amdgcn_cvt_pk_f32_fp8((v).x, false); \
        floatx2 t1 = __builtin_amdgcn_cvt_pk_f32_fp8((v).x, true);  \
        floatx2 t2 = __builtin_amdgcn_cvt_pk_f32_fp8((v).y, false); \
        floatx2 t3 = __builtin_amdgcn_cvt_pk_f32_fp8((v).y, true);  \
        a[0] += t0.x; a[1] += t0.y; a[2] += t1.x; a[3] += t1.y;     \
        a[4] += t2.x; a[5] += t2.y; a[6] += t3.x; a[7] += t3.y;     \
    } while (0)
    for (int e = beg; e < end; e += 16) {
        uint4 s0 = *(const uint4*)&esrc[e];
        uint4 s1 = *(const uint4*)&esrc[e + 8];
        uint2 v[16];
        v[0]  = *(const uint2*)(xq + (size_t)(s0.x & 0xFFFF) * HIDC + loff);
        v[1]  = *(const uint2*)(xq + (size_t)(s0.x >> 16)    * HIDC + loff);
        v[2]  = *(const uint2*)(xq + (size_t)(s0.y & 0xFFFF) * HIDC + loff);
        v[3]  = *(const uint2*)(xq + (size_t)(s0.y >> 16)    * HIDC + loff);
        v[4]  = *(const uint2*)(xq + (size_t)(s0.z & 0xFFFF) * HIDC + loff);
        v[5]  = *(const uint2*)(xq + (size_t)(s0.z >> 16)    * HIDC + loff);
        v[6]  = *(const uint2*)(xq + (size_t)(s0.w & 0xFFFF) * HIDC + loff);
        v[7]  = *(const uint2*)(xq + (size_t)(s0.w >> 16)    * HIDC + loff);
        v[8]  = *(const uint2*)(xq + (size_t)(s1.x & 0xFFFF) * HIDC + loff);
        v[9]  = *(const uint2*)(xq + (size_t)(s1.x >> 16)    * HIDC + loff);
        v[10] = *(const uint2*)(xq + (size_t)(s1.y & 0xFFFF) * HIDC + loff);
        v[11] = *(const uint2*)(xq + (size_t)(s1.y >> 16)    * HIDC + loff);
        v[12] = *(const uint2*)(xq + (size_t)(s1.z & 0xFFFF) * HIDC + loff);
        v[13] = *(const uint2*)(xq + (size_t)(s1.z >> 16)    * HIDC + loff);
        v[14] = *(const uint2*)(xq + (size_t)(s1.w & 0xFFFF) * HIDC + loff);
        v[15] = *(const uint2*)(xq + (size_t)(s1.w >> 16)    * HIDC + loff);
        #pragma unroll
        for (int j = 0; j < 16; j++) ACC8(v[j]);
    }
    #undef ACC8
    float w = 1.0f / (float)max(dn, 1);
    uint2 o;
    o.x = pk4q(a[0] * w, a[1] * w, a[2] * w, a[3] * w);
    o.y = pk4q(a[4] * w, a[5] * w, a[6] * w, a[7] * w);
    *(uint2*)(cq + (size_t)node * HIDC + loff) = o;
}

// ---------------- layer GEMM: 64-row tile, fp8 MFMA, dual 16KB async fp8 panels ----------------
// 782 blocks; weights pipelined one K-step ahead; A-frags read direct from LDS.
// LAST=false: write xq in-place. LAST=true: register-reduce rows per graph -> hg atomics.
template<bool LAST>
__global__ __launch_bounds__(256, 4) void k_lgemm(unsigned char* __restrict__ xq,
        const unsigned char* __restrict__ cq, const unsigned char* __restrict__ wq,
        const float* __restrict__ bias, const int* __restrict__ gid,
        float* __restrict__ hg) {
    __shared__ unsigned long long panelA64[2048];  // 16 KB: 64 rows x 256 B
    __shared__ unsigned long long panelC64[2048];  // 16 KB
    __shared__ float rs[64];
    __shared__ signed char ggl[LAST ? 64 : 1];     // per-row local graph index
    __shared__ int g0s;
    unsigned char* panelA = (unsigned char*)panelA64;
    unsigned char* panelC = (unsigned char*)panelC64;
    int tid = threadIdx.x;
    int w = tid >> 6;
    int lane = tid & 63;
    int quad = lane >> 4;
    int l15 = lane & 15;
    int row0 = blockIdx.x * 64;

    // async stage both fp8 panels (wave w covers bytes [w*4096, w*4096+4096) of each)
    {
        #pragma unroll
        for (int i = 0; i < 4; i++) {
            int ldsoff = w * 4096 + i * 1024 + lane * 16;
            int r = ldsoff >> 8;                  // row 0..63 (256 B/row)
            int ch = (ldsoff & 255) >> 4;         // physical 16B chunk 0..15
            int lc = ch ^ (r & 15);               // logical chunk (XOR swizzle)
            ldscp16(xq + (size_t)(row0 + r) * HIDC + lc * 16, &panelA[w * 4096 + i * 1024]);
            ldscp16(cq + (size_t)(row0 + r) * HIDC + lc * 16, &panelC[w * 4096 + i * 1024]);
        }
    }
    __syncthreads();   // vmcnt drained -> both panels visible

    floatx4 acc[4][4];
    #pragma unroll
    for (int mt = 0; mt < 4; mt++)
        #pragma unroll
        for (int n = 0; n < 4; n++)
            acc[mt][n] = (floatx4){0.f, 0.f, 0.f, 0.f};

    const unsigned char* bp = wq + ((size_t)(w * 4) * 64 + lane) * 8;  // bytes; step stride 8192

    // weights pipelined one K-step ahead (global); A-frags direct ds_read
    long long bcur[4], bnxt[4];
    #pragma unroll
    for (int n = 0; n < 4; n++) bcur[n] = *(const long long*)(bp + n * 512);

    #pragma unroll
    for (int st = 0; st < 16; st++) {
        if (st < 15) {
            const unsigned char* wp = bp + (size_t)(st + 1) * 8192;
            #pragma unroll
            for (int n = 0; n < 4; n++)
                bnxt[n] = *(const long long*)(wp + n * 512);
        }
        const unsigned char* pan = (st < 8) ? panelA : panelC;
        int ks = st & 7;
        long long afr[4];
        #pragma unroll
        for (int mt = 0; mt < 4; mt++) {
            int row = mt * 16 + l15;
            int lc = ks * 2 + (quad >> 1);
            int phys = lc ^ (row & 15);
            afr[mt] = *(const long long*)&pan[row * 256 + phys * 16 + (quad & 1) * 8];
        }
        #pragma unroll
        for (int mt = 0; mt < 4; mt++)
            #pragma unroll
            for (int n = 0; n < 4; n++)
                acc[mt][n] = __builtin_amdgcn_mfma_f32_16x16x32_fp8_fp8(
                    afr[mt], bcur[n], acc[mt][n], 0, 0, 0);
        #pragma unroll
        for (int n = 0; n < 4; n++) bcur[n] = bnxt[n];
    }

    float bv[4];
    #pragma unroll
    for (int n = 0; n < 4; n++) bv[n] = bias[w * 64 + n * 16 + l15];
    #pragma unroll
    for (int mt = 0; mt < 4; mt++)
        #pragma unroll
        for (int n = 0; n < 4; n++)
            #pragma unroll
            for (int r = 0; r < 4; r++)
                acc[mt][n][r] += bv[n];

    // row L2-norm across 4 col-waves
    __syncthreads();
    if (tid < 64) rs[tid] = 0.f;
    if constexpr (LAST) {
        if (tid < 64) {
            int g0 = gid[min(row0, N_NODESC - 1)];
            int gv = gid[min(row0 + tid, N_NODESC - 1)] - g0;
            ggl[tid] = (signed char)min(gv, 3);
            if (tid == 0) g0s = g0;
        }
    }
    __syncthreads();
    #pragma unroll
    for (int mt = 0; mt < 4; mt++) {
        #pragma unroll
        for (int r = 0; r < 4; r++) {
            float p = acc[mt][0][r] * acc[mt][0][r] + acc[mt][1][r] * acc[mt][1][r]
                    + acc[mt][2][r] * acc[mt][2][r] + acc[mt][3][r] * acc[mt][3][r];
            p += __shfl_xor(p, 1);
            p += __shfl_xor(p, 2);
            p += __shfl_xor(p, 4);
            p += __shfl_xor(p, 8);
            if (l15 == 0) atomicAdd(&rs[mt * 16 + quad * 4 + r], p);
        }
    }
    __syncthreads();

    // epilogue: normalize + relu + residual. LAST keeps nv in acc for pooling.
    #pragma unroll
    for (int mt = 0; mt < 4; mt++) {
        #pragma unroll
        for (int r = 0; r < 4; r++) {
            int lrow = mt * 16 + quad * 4 + r;
            int row = row0 + lrow;
            float inv = 1.0f / fmaxf(sqrtf(rs[lrow]), EPSV);
            #pragma unroll
            for (int n = 0; n < 4; n++) {
                // residual base: fp8 x_old from panelA (same value the GEMM used)
                int phys = (w * 4 + n) ^ (lrow & 15);
                float xo = q2f((unsigned)panelA[lrow * 256 + phys * 16 + l15]);
                float nv = xo + fmaxf(acc[mt][n][r] * inv, 0.f);
                if constexpr (LAST) {
                    acc[mt][n][r] = nv;
                } else if (row < N_NODESC) {
                    int col = w * 64 + n * 16 + l15;
                    xq[(size_t)row * HIDC + col] = f2q(nv);
                }
            }
        }
    }
    if constexpr (LAST) {
        // per-graph register reduction over this thread's 16 rows, then shfl
        // across the 4 quads sharing each column, then 1 atomic per column.
        int nspan = (int)ggl[63] + 1;
        int g0 = g0s;
        for (int gl = 0; gl < nspan; gl++) {
            float s[4] = {0.f, 0.f, 0.f, 0.f};
            #pragma unroll
            for (int mt = 0; mt < 4; mt++) {
                #pragma unroll
                for (int r = 0; r < 4; r++) {
                    int lrow = mt * 16 + quad * 4 + r;
                    bool m = ((int)ggl[lrow] == gl) && (row0 + lrow < N_NODESC);
                    float f = m ? 1.f : 0.f;
                    #pragma unroll
                    for (int n = 0; n < 4; n++) s[n] += f * acc[mt][n][r];
                }
            }
            #pragma unroll
            for (int n = 0; n < 4; n++) {
                s[n] += __shfl_xor(s[n], 16);
                s[n] += __shfl_xor(s[n], 32);
            }
            if (quad == 0) {
                #pragma unroll
                for (int n = 0; n < 4; n++)
                    atomicAdd(&hg[(g0 + gl) * HIDC + w * 64 + n * 16 + l15], s[n]);
            }
        }
    }
}

// ---------------- readout (divides pooled sums by node counts) ----------------
__global__ __launch_bounds__(256) void k_readout(const float* __restrict__ hg,
        const int* __restrict__ gstart, const float* __restrict__ ppos,
        const float* __restrict__ pneg, const float* __restrict__ wfc,
        float* __restrict__ out) {
    __shared__ float red[256];
    __shared__ float ss[10];
    int t = threadIdx.x;
    int g = blockIdx.x;
    int beg = gstart[g], end = gstart[g + 1];
    float inv = 1.0f / (float)max(end - beg, 1);
    float hgv = hg[g * HIDC + t] * inv;
    for (int p = 0; p < 10; p++) {
        const float* P = (p < 5) ? (ppos + p * HIDC) : (pneg + (p - 5) * HIDC);
        float d = hgv - P[t];
        red[t] = d * d;
        __syncthreads();
        for (int s2 = 128; s2 > 0; s2 >>= 1) {
            if (t < s2) red[t] += red[t + s2];
            __syncthreads();
        }
        if (t == 0) {
            float dd = red[0];
            ss[p] = logf((dd + 1.0f) / (dd + EPSV));
        }
        __syncthreads();
    }
    if (t == 0) {
        float y = 0.f;
        #pragma unroll
        for (int p = 0; p < 10; p++) y += ss[p] * wfc[p];
        out[g] = 1.0f / (1.0f + expf(-y));
    }
}

extern "C" void kernel_launch(void* const* d_in, const int* in_sizes, int n_in,
                              void* d_out, int out_size, void* d_ws, size_t ws_size,
                              hipStream_t stream) {
    const float* h    = (const float*)d_in[0];
    const int*   src  = (const int*)d_in[1];
    const int*   dst  = (const int*)d_in[2];
    const int*   gid  = (const int*)d_in[3];
    const float* Wemb = (const float*)d_in[4];
    const float* bemb = (const float*)d_in[5];
    const float* Ws   = (const float*)d_in[6];
    const float* bs   = (const float*)d_in[7];
    const float* ppos = (const float*)d_in[8];
    const float* pneg = (const float*)d_in[9];
    const float* wfc  = (const float*)d_in[10];
    float* out = (float*)d_out;

    char* ws = (char*)d_ws;
    size_t off = 0;
    auto alloc = [&](size_t bytes) {
        void* p = ws + off;
        off += (bytes + 255) & ~(size_t)255;
        return p;
    };
    unsigned char*  xq     = (unsigned char*)alloc((size_t)NPAD * HIDC);       // fp8 activation (in-place)
    unsigned char*  cq     = (unsigned char*)alloc((size_t)NPAD * HIDC);       // fp8 aggregate out
    unsigned short* wsw    = (unsigned short*)alloc((size_t)(IN_DIMC * HIDC) * 2);          // bf16 embed W
    unsigned char*  wq     = (unsigned char*)alloc((size_t)(N_LAYERSC * 2 * HIDC * HIDC)); // fp8 layer W
    int*            offs   = (int*)alloc((size_t)(N_NODESC + 1) * 4);
    int*            ndeg   = (int*)alloc((size_t)N_NODESC * 4);
    unsigned short* esrc   = (unsigned short*)alloc((size_t)NBUCK * PBUCK * 2);  // padded slabs
    unsigned*       ebpack = (unsigned*)alloc((size_t)N_EDGESC * 4);
    int*            gbcnt  = (int*)alloc((size_t)NBUCK * 4);
    int*            boffB  = (int*)alloc((size_t)(NBUCK + 1) * 4);
    int*            gcurB  = (int*)alloc((size_t)NBUCK * 4);
    int*            gstart = (int*)alloc((size_t)(N_GRAPHSC + 1) * 4);
    float*          hg     = (float*)alloc((size_t)N_GRAPHSC * HIDC * 4);
    (void)ws_size; (void)in_sizes; (void)n_in; (void)out_size;

    hipMemsetAsync(gbcnt, 0, (size_t)NBUCK * 4, stream);
    hipMemsetAsync(hg, 0, (size_t)N_GRAPHSC * HIDC * 4, stream);

    const int LYR = 2 * HIDC * HIDC;
    // wconv | gbounds | bcount (mutually independent roles)
    k_pre1<<<WCONV_BLKS + 1 + NBLK1, 256, 0, stream>>>(Wemb, Ws, wsw, wq, gid, gstart, dst, gbcnt);
    k_bscan<<<1, 256, 0, stream>>>(gbcnt, boffB, gcurB);
    // bscatter | embed GEMM (independent roles; embed hides under scatter pass)
    k_scat_egemm<<<NBLK1 + NPAD / 32, 256, 0, stream>>>(src, dst, gcurB, ebpack, h, wsw, bemb, xq);
    k_bbuild<<<NBUCK, 256, 0, stream>>>(ebpack, boffB, offs, ndeg, esrc);

    for (int l = 0; l < N_LAYERSC; l++) {
        k_aggregate<<<(N_NODESC * 32) / 256, 256, 0, stream>>>(xq, offs, ndeg, esrc, cq);
        if (l < N_LAYERSC - 1)
            k_lgemm<false><<<NPAD / 64, 256, 0, stream>>>(
                xq, cq, wq + (size_t)l * LYR, bs + (size_t)l * HIDC, gid, hg);
        else
            k_lgemm<true><<<NPAD / 64, 256, 0, stream>>>(
                xq, cq, wq + (size_t)l * LYR, bs + (size_t)l * HIDC, gid, hg);
    }
    k_readout<<<N_GRAPHSC, 256, 0, stream>>>(hg, gstart, ppos, pneg, wfc, out);
}

// Round 9
// 343.342 us; speedup vs baseline: 1.0389x; 1.0389x over previous
//
#include <hip/hip_runtime.h>
#include <math.h>

#define N_NODESC 50000
#define NPAD 50048              // 1564 * 32
#define N_EDGESC 800000
#define N_GRAPHSC 64
#define IN_DIMC 128
#define HIDC 256
#define N_LAYERSC 4
#define EPSV 1e-12f

#define NBUCK 196               // buckets of 256 nodes
#define EPB 4096
#define NBLK1 196               // ceil(800000/4096)
#define WCONV_BLKS 2176         // 557056 / 256
#define ESLAB 8192              // fixed ebpack slab per bucket (max bucket ~4400)
#define PBUCK 8192              // padded esrc slab entries per bucket (pad-8)
#define ZROW 50000              // dedicated zero row in xq (egemm writes 0)

typedef __attribute__((ext_vector_type(8))) short short8;
typedef __attribute__((ext_vector_type(4))) float floatx4;
typedef __attribute__((ext_vector_type(2))) float floatx2;

__device__ __forceinline__ unsigned short f2b(float f) {
    union { float f; unsigned u; } v; v.f = f;
    unsigned r = v.u + 0x7FFFu + ((v.u >> 16) & 1u);
    return (unsigned short)(r >> 16);
}
__device__ __forceinline__ unsigned pkb(float a, float b) {
    return (unsigned)f2b(a) | ((unsigned)f2b(b) << 16);
}
__device__ __forceinline__ unsigned char f2q(float v) {
    return (unsigned char)(__builtin_amdgcn_cvt_pk_fp8_f32(v, v, 0, false) & 0xFF);
}
__device__ __forceinline__ float q2f(unsigned u) {
    floatx2 t = __builtin_amdgcn_cvt_pk_f32_fp8(u, false);
    return t.x;   // converts byte 0
}
__device__ __forceinline__ unsigned pk4q(float a, float b, float c, float d) {
    unsigned lo = (unsigned)__builtin_amdgcn_cvt_pk_fp8_f32(a, b, 0, false) & 0xFFFFu;
    unsigned hi = (unsigned)__builtin_amdgcn_cvt_pk_fp8_f32(c, d, 0, false) << 16;
    return lo | hi;
}
__device__ __forceinline__ void ldscp16(const void* g, void* l) {
    __builtin_amdgcn_global_load_lds(
        (const __attribute__((address_space(1))) unsigned int*)g,
        (__attribute__((address_space(3))) unsigned int*)l, 16, 0, 0);
}

// ---------------- K1: weight convert | graph bounds | bucket scatter+count ----------------
// Scatter writes into fixed per-bucket slabs (base via zeroed gcurB cursor); the cursor's
// final value is the bucket count -> no prefix scan, no separate count pass.
__global__ __launch_bounds__(256) void k_pre1(const float* __restrict__ Wemb,
        const float* __restrict__ Ws, unsigned short* __restrict__ wsw,
        unsigned char* __restrict__ wq, const int* __restrict__ gid,
        int* __restrict__ gstart, const int* __restrict__ src,
        const int* __restrict__ dst, int* __restrict__ gcurB,
        unsigned* __restrict__ ebpack) {
    __shared__ int bc[256];
    __shared__ int cur[256];
    int b = blockIdx.x;
    int t = threadIdx.x;
    if (b < WCONV_BLKS) {
        int idx = b * 256 + t;
        const int EMB = IN_DIMC * HIDC;           // 32768
        const int LYR = 2 * HIDC * HIDC;          // 131072
        if (idx < EMB) {
            int k = idx >> 8, n = idx & 255;
            int off = (((k >> 5) * 16 + (n >> 4)) * 64 + ((((k >> 3) & 3) << 4) | (n & 15))) * 8 + (k & 7);
            wsw[off] = f2b(Wemb[idx]);
        } else if (idx < EMB + N_LAYERSC * LYR) {
            int r = idx - EMB;
            int l = r >> 17;
            int r2 = r & (LYR - 1);
            int k = r2 >> 8, n = r2 & 255;
            int off = (((k >> 5) * 16 + (n >> 4)) * 64 + ((((k >> 3) & 3) << 4) | (n & 15))) * 8 + (k & 7);
            wq[(size_t)l * LYR + off] = f2q(Ws[r]);
        }
    } else if (b == WCONV_BLKS) {
        int g = t;
        if (g <= N_GRAPHSC) {
            int lo = 0, hi = N_NODESC;
            while (lo < hi) {
                int mid = (lo + hi) >> 1;
                if (gid[mid] < g) lo = mid + 1; else hi = mid;
            }
            gstart[g] = lo;
        }
    } else {
        int sb = b - WCONV_BLKS - 1;
        bc[t] = 0;
        __syncthreads();
        int e0 = sb * EPB;
        for (int i = t; i < EPB; i += 256) {
            int e = e0 + i;
            if (e < N_EDGESC) atomicAdd(&bc[dst[e] >> 8], 1);
        }
        __syncthreads();
        if (t < NBUCK)
            cur[t] = (bc[t] > 0) ? atomicAdd(&gcurB[t], bc[t]) : 0;
        __syncthreads();
        for (int i = t; i < EPB; i += 256) {
            int e = e0 + i;
            if (e < N_EDGESC) {
                int d = dst[e];
                int bk = d >> 8;
                int pos = atomicAdd(&cur[bk], 1);
                ebpack[(size_t)bk * ESLAB + pos] = (unsigned)src[e] | ((unsigned)(d & 255) << 16);
            }
        }
    }
}

// ---------------- K2: CSR build (8-padded slabs) | embed GEMM (independent roles) ----------------
__global__ __launch_bounds__(256, 4) void k_build_egemm(const unsigned* __restrict__ ebpack,
        const int* __restrict__ gcurB, int* __restrict__ offs, int* __restrict__ ndeg,
        unsigned short* __restrict__ esrc, const float* __restrict__ h,
        const unsigned short* __restrict__ wsw, const float* __restrict__ bias,
        unsigned char* __restrict__ xq) {
    __shared__ int deg[256];
    __shared__ int lofs[256];
    __shared__ unsigned short img[PBUCK];     // 16 KB
    if (blockIdx.x < NBUCK) {
        // ---- bbuild role (verified R4/R6): pad lists to x8, pads -> ZROW ----
        int b = blockIdx.x;
        int t = threadIdx.x;
        size_t bbase = (size_t)b * ESLAB;
        int cnt = gcurB[b];
        deg[t] = 0;
        __syncthreads();
        for (int i = t; i < cnt; i += 256)
            atomicAdd(&deg[ebpack[bbase + i] >> 16], 1);
        __syncthreads();
        int d = deg[t];
        int pd = (d + 7) & ~7;                // pad each list to multiple of 8
        lofs[t] = pd;
        __syncthreads();
        for (int s = 1; s < 256; s <<= 1) {
            int u = (t >= s) ? lofs[t - s] : 0;
            __syncthreads();
            lofs[t] += u;
            __syncthreads();
        }
        int pexcl = lofs[t] - pd;
        int node = b * 256 + t;
        int S = b * PBUCK;
        if (node < N_NODESC) {
            offs[node] = S + pexcl;
            ndeg[node] = d;
        }
        int ptot = lofs[255];
        for (int i = t; i < ptot; i += 256) img[i] = (unsigned short)ZROW;
        deg[t] = pexcl;                       // scatter cursor
        __syncthreads();
        for (int i = t; i < cnt; i += 256) {
            unsigned p = ebpack[bbase + i];
            int pos = atomicAdd(&deg[p >> 16], 1);
            img[pos] = (unsigned short)(p & 0xFFFF);
        }
        __syncthreads();
        for (int i = t; i < ptot; i += 256)
            esrc[S + i] = img[i];
        return;
    }
    // ---- embed GEMM role ----
    int tid = threadIdx.x;
    int wn = tid >> 6;
    int lane = tid & 63;
    int quad = lane >> 4;
    int l15 = lane & 15;
    int row0 = (blockIdx.x - NBUCK) * 32;

    floatx4 acc[2][4];
    #pragma unroll
    for (int mt = 0; mt < 2; mt++)
        #pragma unroll
        for (int n = 0; n < 4; n++)
            acc[mt][n] = (floatx4){0.f, 0.f, 0.f, 0.f};

    int r0 = row0 + l15;
    int r1 = row0 + 16 + l15;
    bool ok0 = r0 < N_NODESC, ok1 = r1 < N_NODESC;
    const float* h0 = h + (size_t)r0 * IN_DIMC + quad * 8;
    const float* h1 = h + (size_t)r1 * IN_DIMC + quad * 8;
    const unsigned short* bp = wsw + ((size_t)(wn * 4) * 64 + lane) * 8;

    #pragma unroll
    for (int ks = 0; ks < 4; ks++) {
        float4 f00 = ok0 ? *(const float4*)(h0 + ks * 32)     : (float4){0,0,0,0};
        float4 f01 = ok0 ? *(const float4*)(h0 + ks * 32 + 4) : (float4){0,0,0,0};
        float4 f10 = ok1 ? *(const float4*)(h1 + ks * 32)     : (float4){0,0,0,0};
        float4 f11 = ok1 ? *(const float4*)(h1 + ks * 32 + 4) : (float4){0,0,0,0};
        short8 afr[2], bfr[4];
        uint4 av;
        av.x = pkb(f00.x, f00.y); av.y = pkb(f00.z, f00.w);
        av.z = pkb(f01.x, f01.y); av.w = pkb(f01.z, f01.w);
        afr[0] = *(short8*)&av;
        av.x = pkb(f10.x, f10.y); av.y = pkb(f10.z, f10.w);
        av.z = pkb(f11.x, f11.y); av.w = pkb(f11.z, f11.w);
        afr[1] = *(short8*)&av;
        const unsigned short* wp = bp + (size_t)ks * 8192;
        #pragma unroll
        for (int n = 0; n < 4; n++)
            bfr[n] = *(const short8*)(wp + n * 512);
        #pragma unroll
        for (int mt = 0; mt < 2; mt++)
            #pragma unroll
            for (int n = 0; n < 4; n++)
                acc[mt][n] = __builtin_amdgcn_mfma_f32_16x16x32_bf16(
                    afr[mt], bfr[n], acc[mt][n], 0, 0, 0);
    }

    float bv[4];
    #pragma unroll
    for (int n = 0; n < 4; n++) bv[n] = bias[wn * 64 + n * 16 + l15];
    #pragma unroll
    for (int mt = 0; mt < 2; mt++) {
        #pragma unroll
        for (int r = 0; r < 4; r++) {
            int row = row0 + mt * 16 + quad * 4 + r;
            #pragma unroll
            for (int n = 0; n < 4; n++) {
                int col = wn * 64 + n * 16 + l15;
                // pad rows (incl. ZROW) written as 0 so gather padding adds nothing
                float v = acc[mt][n][r] + bv[n];
                xq[(size_t)row * HIDC + col] = (row < N_NODESC) ? f2q(v) : (unsigned char)0;
            }
        }
    }
}

// ---------------- per-node mean aggregation: 32 lanes x 8B, vectorized indices ----------------
// R7-verified. Near LLC-BW roofline (205 MB/layer of random 256B rows @ ~7 TB/s).
__global__ __launch_bounds__(256, 8) void k_aggregate(const unsigned char* __restrict__ xq,
        const int* __restrict__ offs, const int* __restrict__ ndeg,
        const unsigned short* __restrict__ esrc, unsigned char* __restrict__ cq) {
    int gidx = blockIdx.x * 256 + threadIdx.x;
    int node = gidx >> 5;                     // grid exact: 6250 blocks * 8 nodes
    int lane = threadIdx.x & 31;
    int beg = offs[node];
    int dn = ndeg[node];
    int pd = (dn + 7) & ~7;
    int end = beg + pd;
    float a[8];
    #pragma unroll
    for (int j = 0; j < 8; j++) a[j] = 0.f;
    size_t loff = (size_t)lane * 8;
    #define ACC8(v) do { \
        floatx2 t0 = __builtin_amdgcn_cvt_pk_f32_fp8((v).x, false); \
        floatx2 t1 = __builtin_amdgcn_cvt_pk_f32_fp8((v).x, true);  \
        floatx2 t2 = __builtin_amdgcn_cvt_pk_f32_fp8((v).y, false); \
        floatx2 t3 = __builtin_amdgcn_cvt_pk_f32_fp8((v).y, true);  \
        a[0] += t0.x; a[1] += t0.y; a[2] += t1.x; a[3] += t1.y;     \
        a[4] += t2.x; a[5] += t2.y; a[6] += t3.x; a[7] += t3.y;     \
    } while (0)
    if (pd > 0) {
        uint4 si = *(const uint4*)&esrc[beg];     // 8 indices, one 16B load
        for (int e = beg; e < end; e += 8) {
            uint4 sn;
            if (e + 8 < end) sn = *(const uint4*)&esrc[e + 8];
            uint2 v[8];
            v[0] = *(const uint2*)(xq + (size_t)(si.x & 0xFFFF) * HIDC + loff);
            v[1] = *(const uint2*)(xq + (size_t)(si.x >> 16)    * HIDC + loff);
            v[2] = *(const uint2*)(xq + (size_t)(si.y & 0xFFFF) * HIDC + loff);
            v[3] = *(const uint2*)(xq + (size_t)(si.y >> 16)    * HIDC + loff);
            v[4] = *(const uint2*)(xq + (size_t)(si.z & 0xFFFF) * HIDC + loff);
            v[5] = *(const uint2*)(xq + (size_t)(si.z >> 16)    * HIDC + loff);
            v[6] = *(const uint2*)(xq + (size_t)(si.w & 0xFFFF) * HIDC + loff);
            v[7] = *(const uint2*)(xq + (size_t)(si.w >> 16)    * HIDC + loff);
            #pragma unroll
            for (int j = 0; j < 8; j++) ACC8(v[j]);
            si = sn;
        }
    }
    #undef ACC8
    float w = 1.0f / (float)max(dn, 1);
    uint2 o;
    o.x = pk4q(a[0] * w, a[1] * w, a[2] * w, a[3] * w);
    o.y = pk4q(a[4] * w, a[5] * w, a[6] * w, a[7] * w);
    *(uint2*)(cq + (size_t)node * HIDC + loff) = o;
}

// ---------------- layer GEMM: 64-row tile, fp8 MFMA, dual 16KB async fp8 panels ----------------
// R7-verified. Weights pipelined one K-step ahead; A-frags direct ds_read.
// LAST=false: write xq in-place. LAST=true: register-reduce rows per graph -> hg atomics.
template<bool LAST>
__global__ __launch_bounds__(256, 4) void k_lgemm(unsigned char* __restrict__ xq,
        const unsigned char* __restrict__ cq, const unsigned char* __restrict__ wq,
        const float* __restrict__ bias, const int* __restrict__ gid,
        float* __restrict__ hg) {
    __shared__ unsigned long long panelA64[2048];  // 16 KB: 64 rows x 256 B
    __shared__ unsigned long long panelC64[2048];  // 16 KB
    __shared__ float rs[64];
    __shared__ signed char ggl[LAST ? 64 : 1];     // per-row local graph index
    __shared__ int g0s;
    unsigned char* panelA = (unsigned char*)panelA64;
    unsigned char* panelC = (unsigned char*)panelC64;
    int tid = threadIdx.x;
    int w = tid >> 6;
    int lane = tid & 63;
    int quad = lane >> 4;
    int l15 = lane & 15;
    int row0 = blockIdx.x * 64;

    // async stage both fp8 panels (wave w covers bytes [w*4096, w*4096+4096) of each)
    {
        #pragma unroll
        for (int i = 0; i < 4; i++) {
            int ldsoff = w * 4096 + i * 1024 + lane * 16;
            int r = ldsoff >> 8;                  // row 0..63 (256 B/row)
            int ch = (ldsoff & 255) >> 4;         // physical 16B chunk 0..15
            int lc = ch ^ (r & 15);               // logical chunk (XOR swizzle)
            ldscp16(xq + (size_t)(row0 + r) * HIDC + lc * 16, &panelA[w * 4096 + i * 1024]);
            ldscp16(cq + (size_t)(row0 + r) * HIDC + lc * 16, &panelC[w * 4096 + i * 1024]);
        }
    }
    __syncthreads();   // vmcnt drained -> both panels visible

    floatx4 acc[4][4];
    #pragma unroll
    for (int mt = 0; mt < 4; mt++)
        #pragma unroll
        for (int n = 0; n < 4; n++)
            acc[mt][n] = (floatx4){0.f, 0.f, 0.f, 0.f};

    const unsigned char* bp = wq + ((size_t)(w * 4) * 64 + lane) * 8;  // bytes; step stride 8192

    // weights pipelined one K-step ahead (global); A-frags direct ds_read
    long long bcur[4], bnxt[4];
    #pragma unroll
    for (int n = 0; n < 4; n++) bcur[n] = *(const long long*)(bp + n * 512);

    #pragma unroll
    for (int st = 0; st < 16; st++) {
        if (st < 15) {
            const unsigned char* wp = bp + (size_t)(st + 1) * 8192;
            #pragma unroll
            for (int n = 0; n < 4; n++)
                bnxt[n] = *(const long long*)(wp + n * 512);
        }
        const unsigned char* pan = (st < 8) ? panelA : panelC;
        int ks = st & 7;
        long long afr[4];
        #pragma unroll
        for (int mt = 0; mt < 4; mt++) {
            int row = mt * 16 + l15;
            int lc = ks * 2 + (quad >> 1);
            int phys = lc ^ (row & 15);
            afr[mt] = *(const long long*)&pan[row * 256 + phys * 16 + (quad & 1) * 8];
        }
        #pragma unroll
        for (int mt = 0; mt < 4; mt++)
            #pragma unroll
            for (int n = 0; n < 4; n++)
                acc[mt][n] = __builtin_amdgcn_mfma_f32_16x16x32_fp8_fp8(
                    afr[mt], bcur[n], acc[mt][n], 0, 0, 0);
        #pragma unroll
        for (int n = 0; n < 4; n++) bcur[n] = bnxt[n];
    }

    float bv[4];
    #pragma unroll
    for (int n = 0; n < 4; n++) bv[n] = bias[w * 64 + n * 16 + l15];
    #pragma unroll
    for (int mt = 0; mt < 4; mt++)
        #pragma unroll
        for (int n = 0; n < 4; n++)
            #pragma unroll
            for (int r = 0; r < 4; r++)
                acc[mt][n][r] += bv[n];

    // row L2-norm across 4 col-waves
    __syncthreads();
    if (tid < 64) rs[tid] = 0.f;
    if constexpr (LAST) {
        if (tid < 64) {
            int g0 = gid[min(row0, N_NODESC - 1)];
            int gv = gid[min(row0 + tid, N_NODESC - 1)] - g0;
            ggl[tid] = (signed char)min(gv, 3);
            if (tid == 0) g0s = g0;
        }
    }
    __syncthreads();
    #pragma unroll
    for (int mt = 0; mt < 4; mt++) {
        #pragma unroll
        for (int r = 0; r < 4; r++) {
            float p = acc[mt][0][r] * acc[mt][0][r] + acc[mt][1][r] * acc[mt][1][r]
                    + acc[mt][2][r] * acc[mt][2][r] + acc[mt][3][r] * acc[mt][3][r];
            p += __shfl_xor(p, 1);
            p += __shfl_xor(p, 2);
            p += __shfl_xor(p, 4);
            p += __shfl_xor(p, 8);
            if (l15 == 0) atomicAdd(&rs[mt * 16 + quad * 4 + r], p);
        }
    }
    __syncthreads();

    // epilogue: normalize + relu + residual. LAST keeps nv in acc for pooling.
    #pragma unroll
    for (int mt = 0; mt < 4; mt++) {
        #pragma unroll
        for (int r = 0; r < 4; r++) {
            int lrow = mt * 16 + quad * 4 + r;
            int row = row0 + lrow;
            float inv = 1.0f / fmaxf(sqrtf(rs[lrow]), EPSV);
            #pragma unroll
            for (int n = 0; n < 4; n++) {
                // residual base: fp8 x_old from panelA (same value the GEMM used)
                int phys = (w * 4 + n) ^ (lrow & 15);
                float xo = q2f((unsigned)panelA[lrow * 256 + phys * 16 + l15]);
                float nv = xo + fmaxf(acc[mt][n][r] * inv, 0.f);
                if constexpr (LAST) {
                    acc[mt][n][r] = nv;
                } else if (row < N_NODESC) {
                    int col = w * 64 + n * 16 + l15;
                    xq[(size_t)row * HIDC + col] = f2q(nv);
                }
            }
        }
    }
    if constexpr (LAST) {
        // per-graph register reduction over this thread's 16 rows, then shfl
        // across the 4 quads sharing each column, then 1 atomic per column.
        int nspan = (int)ggl[63] + 1;
        int g0 = g0s;
        for (int gl = 0; gl < nspan; gl++) {
            float s[4] = {0.f, 0.f, 0.f, 0.f};
            #pragma unroll
            for (int mt = 0; mt < 4; mt++) {
                #pragma unroll
                for (int r = 0; r < 4; r++) {
                    int lrow = mt * 16 + quad * 4 + r;
                    bool m = ((int)ggl[lrow] == gl) && (row0 + lrow < N_NODESC);
                    float f = m ? 1.f : 0.f;
                    #pragma unroll
                    for (int n = 0; n < 4; n++) s[n] += f * acc[mt][n][r];
                }
            }
            #pragma unroll
            for (int n = 0; n < 4; n++) {
                s[n] += __shfl_xor(s[n], 16);
                s[n] += __shfl_xor(s[n], 32);
            }
            if (quad == 0) {
                #pragma unroll
                for (int n = 0; n < 4; n++)
                    atomicAdd(&hg[(g0 + gl) * HIDC + w * 64 + n * 16 + l15], s[n]);
            }
        }
    }
}

// ---------------- readout: per-wave shfl reduce, single barrier ----------------
__global__ __launch_bounds__(256) void k_readout(const float* __restrict__ hg,
        const int* __restrict__ gstart, const float* __restrict__ ppos,
        const float* __restrict__ pneg, const float* __restrict__ wfc,
        float* __restrict__ out) {
    __shared__ float part[10][4];
    int t = threadIdx.x;
    int g = blockIdx.x;
    int wv = t >> 6;
    int ln = t & 63;
    int beg = gstart[g], end = gstart[g + 1];
    float inv = 1.0f / (float)max(end - beg, 1);
    float hgv = hg[g * HIDC + t] * inv;
    #pragma unroll
    for (int p = 0; p < 10; p++) {
        const float* P = (p < 5) ? (ppos + p * HIDC) : (pneg + (p - 5) * HIDC);
        float d = hgv - P[t];
        float sq = d * d;
        sq += __shfl_xor(sq, 1);
        sq += __shfl_xor(sq, 2);
        sq += __shfl_xor(sq, 4);
        sq += __shfl_xor(sq, 8);
        sq += __shfl_xor(sq, 16);
        sq += __shfl_xor(sq, 32);
        if (ln == 0) part[p][wv] = sq;
    }
    __syncthreads();
    if (t == 0) {
        float y = 0.f;
        #pragma unroll
        for (int p = 0; p < 10; p++) {
            float dd = part[p][0] + part[p][1] + part[p][2] + part[p][3];
            y += logf((dd + 1.0f) / (dd + EPSV)) * wfc[p];
        }
        out[g] = 1.0f / (1.0f + expf(-y));
    }
}

extern "C" void kernel_launch(void* const* d_in, const int* in_sizes, int n_in,
                              void* d_out, int out_size, void* d_ws, size_t ws_size,
                              hipStream_t stream) {
    const float* h    = (const float*)d_in[0];
    const int*   src  = (const int*)d_in[1];
    const int*   dst  = (const int*)d_in[2];
    const int*   gid  = (const int*)d_in[3];
    const float* Wemb = (const float*)d_in[4];
    const float* bemb = (const float*)d_in[5];
    const float* Ws   = (const float*)d_in[6];
    const float* bs   = (const float*)d_in[7];
    const float* ppos = (const float*)d_in[8];
    const float* pneg = (const float*)d_in[9];
    const float* wfc  = (const float*)d_in[10];
    float* out = (float*)d_out;

    char* ws = (char*)d_ws;
    size_t off = 0;
    auto alloc = [&](size_t bytes) {
        void* p = ws + off;
        off += (bytes + 255) & ~(size_t)255;
        return p;
    };
    unsigned char*  xq     = (unsigned char*)alloc((size_t)NPAD * HIDC);       // fp8 activation (in-place)
    unsigned char*  cq     = (unsigned char*)alloc((size_t)NPAD * HIDC);       // fp8 aggregate out
    unsigned short* wsw    = (unsigned short*)alloc((size_t)(IN_DIMC * HIDC) * 2);          // bf16 embed W
    unsigned char*  wq     = (unsigned char*)alloc((size_t)(N_LAYERSC * 2 * HIDC * HIDC)); // fp8 layer W
    int*            offs   = (int*)alloc((size_t)(N_NODESC + 1) * 4);
    int*            ndeg   = (int*)alloc((size_t)N_NODESC * 4);
    unsigned short* esrc   = (unsigned short*)alloc((size_t)NBUCK * PBUCK * 2);  // padded slabs
    unsigned*       ebpack = (unsigned*)alloc((size_t)NBUCK * ESLAB * 4);        // fixed slabs
    int*            gcurB  = (int*)alloc((size_t)NBUCK * 4);
    int*            gstart = (int*)alloc((size_t)(N_GRAPHSC + 1) * 4);
    float*          hg     = (float*)alloc((size_t)N_GRAPHSC * HIDC * 4);
    (void)ws_size; (void)in_sizes; (void)n_in; (void)out_size;

    hipMemsetAsync(gcurB, 0, (size_t)NBUCK * 4, stream);
    hipMemsetAsync(hg, 0, (size_t)N_GRAPHSC * HIDC * 4, stream);

    const int LYR = 2 * HIDC * HIDC;
    // wconv | gbounds | scatter+count (all independent)
    k_pre1<<<WCONV_BLKS + 1 + NBLK1, 256, 0, stream>>>(Wemb, Ws, wsw, wq, gid, gstart, src, dst, gcurB, ebpack);
    // bbuild | embed GEMM (both depend only on K1; mutually independent)
    k_build_egemm<<<NBUCK + NPAD / 32, 256, 0, stream>>>(ebpack, gcurB, offs, ndeg, esrc, h, wsw, bemb, xq);

    for (int l = 0; l < N_LAYERSC; l++) {
        k_aggregate<<<(N_NODESC * 32) / 256, 256, 0, stream>>>(xq, offs, ndeg, esrc, cq);
        if (l < N_LAYERSC - 1)
            k_lgemm<false><<<NPAD / 64, 256, 0, stream>>>(
                xq, cq, wq + (size_t)l * LYR, bs + (size_t)l * HIDC, gid, hg);
        else
            k_lgemm<true><<<NPAD / 64, 256, 0, stream>>>(
                xq, cq, wq + (size_t)l * LYR, bs + (size_t)l * HIDC, gid, hg);
    }
    k_readout<<<N_GRAPHSC, 256, 0, stream>>>(hg, gstart, ppos, pneg, wfc, out);
}

// Round 11
// 342.388 us; speedup vs baseline: 1.0418x; 1.0028x over previous
//
#include <hip/hip_runtime.h>
#include <math.h>

#define N_NODESC 50000
#define NPAD 50048              // 1564 * 32
#define N_EDGESC 800000
#define N_GRAPHSC 64
#define IN_DIMC 128
#define HIDC 256
#define N_LAYERSC 4
#define EPSV 1e-12f

#define NBUCK 196               // buckets of 256 nodes
#define EPB 4096
#define NBLK1 196               // ceil(800000/4096)
#define WCONV_BLKS 2176         // 557056 / 256
#define ESLAB 8192              // fixed ebpack slab per bucket (max bucket ~4400)
#define PBUCK 8192              // padded esrc slab entries per bucket (pad-8)
#define ZROW 50000              // dedicated zero row in xq (egemm writes 0)

typedef __attribute__((ext_vector_type(8))) short short8;
typedef __attribute__((ext_vector_type(4))) float floatx4;
typedef __attribute__((ext_vector_type(2))) float floatx2;

__device__ __forceinline__ unsigned short f2b(float f) {
    union { float f; unsigned u; } v; v.f = f;
    unsigned r = v.u + 0x7FFFu + ((v.u >> 16) & 1u);
    return (unsigned short)(r >> 16);
}
__device__ __forceinline__ unsigned pkb(float a, float b) {
    return (unsigned)f2b(a) | ((unsigned)f2b(b) << 16);
}
__device__ __forceinline__ unsigned char f2q(float v) {
    return (unsigned char)(__builtin_amdgcn_cvt_pk_fp8_f32(v, v, 0, false) & 0xFF);
}
__device__ __forceinline__ float q2f(unsigned u) {
    floatx2 t = __builtin_amdgcn_cvt_pk_f32_fp8(u, false);
    return t.x;   // converts byte 0
}
__device__ __forceinline__ unsigned pk4q(float a, float b, float c, float d) {
    unsigned lo = (unsigned)__builtin_amdgcn_cvt_pk_fp8_f32(a, b, 0, false) & 0xFFFFu;
    unsigned hi = (unsigned)__builtin_amdgcn_cvt_pk_fp8_f32(c, d, 0, false) << 16;
    return lo | hi;
}
__device__ __forceinline__ void ldscp16(const void* g, void* l) {
    __builtin_amdgcn_global_load_lds(
        (const __attribute__((address_space(1))) unsigned int*)g,
        (__attribute__((address_space(3))) unsigned int*)l, 16, 0, 0);
}

// ---------------- K1: weight convert | graph bounds | bucket scatter+count ----------------
// Scatter writes into fixed per-bucket slabs (base via zeroed gcurB cursor); the cursor's
// final value is the bucket count -> no prefix scan, no separate count pass.
__global__ __launch_bounds__(256) void k_pre1(const float* __restrict__ Wemb,
        const float* __restrict__ Ws, unsigned short* __restrict__ wsw,
        unsigned char* __restrict__ wq, const int* __restrict__ gid,
        int* __restrict__ gstart, const int* __restrict__ src,
        const int* __restrict__ dst, int* __restrict__ gcurB,
        unsigned* __restrict__ ebpack) {
    __shared__ int bc[256];
    __shared__ int cur[256];
    int b = blockIdx.x;
    int t = threadIdx.x;
    if (b < WCONV_BLKS) {
        int idx = b * 256 + t;
        const int EMB = IN_DIMC * HIDC;           // 32768
        const int LYR = 2 * HIDC * HIDC;          // 131072
        if (idx < EMB) {
            int k = idx >> 8, n = idx & 255;
            int off = (((k >> 5) * 16 + (n >> 4)) * 64 + ((((k >> 3) & 3) << 4) | (n & 15))) * 8 + (k & 7);
            wsw[off] = f2b(Wemb[idx]);
        } else if (idx < EMB + N_LAYERSC * LYR) {
            int r = idx - EMB;
            int l = r >> 17;
            int r2 = r & (LYR - 1);
            int k = r2 >> 8, n = r2 & 255;
            int off = (((k >> 5) * 16 + (n >> 4)) * 64 + ((((k >> 3) & 3) << 4) | (n & 15))) * 8 + (k & 7);
            wq[(size_t)l * LYR + off] = f2q(Ws[r]);
        }
    } else if (b == WCONV_BLKS) {
        int g = t;
        if (g <= N_GRAPHSC) {
            int lo = 0, hi = N_NODESC;
            while (lo < hi) {
                int mid = (lo + hi) >> 1;
                if (gid[mid] < g) lo = mid + 1; else hi = mid;
            }
            gstart[g] = lo;
        }
    } else {
        int sb = b - WCONV_BLKS - 1;
        bc[t] = 0;
        __syncthreads();
        int e0 = sb * EPB;
        for (int i = t; i < EPB; i += 256) {
            int e = e0 + i;
            if (e < N_EDGESC) atomicAdd(&bc[dst[e] >> 8], 1);
        }
        __syncthreads();
        if (t < NBUCK)
            cur[t] = (bc[t] > 0) ? atomicAdd(&gcurB[t], bc[t]) : 0;
        __syncthreads();
        for (int i = t; i < EPB; i += 256) {
            int e = e0 + i;
            if (e < N_EDGESC) {
                int d = dst[e];
                int bk = d >> 8;
                int pos = atomicAdd(&cur[bk], 1);
                ebpack[(size_t)bk * ESLAB + pos] = (unsigned)src[e] | ((unsigned)(d & 255) << 16);
            }
        }
    }
}

// ---------------- K2: CSR build (8-padded slabs) | embed GEMM (independent roles) ----------------
__global__ __launch_bounds__(256, 4) void k_build_egemm(const unsigned* __restrict__ ebpack,
        const int* __restrict__ gcurB, int* __restrict__ offs, int* __restrict__ ndeg,
        unsigned short* __restrict__ esrc, const float* __restrict__ h,
        const unsigned short* __restrict__ wsw, const float* __restrict__ bias,
        unsigned char* __restrict__ xq) {
    __shared__ int deg[256];
    __shared__ int lofs[256];
    __shared__ unsigned short img[PBUCK];     // 16 KB
    if (blockIdx.x < NBUCK) {
        // ---- bbuild role (verified R4/R6): pad lists to x8, pads -> ZROW ----
        int b = blockIdx.x;
        int t = threadIdx.x;
        size_t bbase = (size_t)b * ESLAB;
        int cnt = gcurB[b];
        deg[t] = 0;
        __syncthreads();
        for (int i = t; i < cnt; i += 256)
            atomicAdd(&deg[ebpack[bbase + i] >> 16], 1);
        __syncthreads();
        int d = deg[t];
        int pd = (d + 7) & ~7;                // pad each list to multiple of 8
        lofs[t] = pd;
        __syncthreads();
        for (int s = 1; s < 256; s <<= 1) {
            int u = (t >= s) ? lofs[t - s] : 0;
            __syncthreads();
            lofs[t] += u;
            __syncthreads();
        }
        int pexcl = lofs[t] - pd;
        int node = b * 256 + t;
        int S = b * PBUCK;
        if (node < N_NODESC) {
            offs[node] = S + pexcl;
            ndeg[node] = d;
        }
        int ptot = lofs[255];
        for (int i = t; i < ptot; i += 256) img[i] = (unsigned short)ZROW;
        deg[t] = pexcl;                       // scatter cursor
        __syncthreads();
        for (int i = t; i < cnt; i += 256) {
            unsigned p = ebpack[bbase + i];
            int pos = atomicAdd(&deg[p >> 16], 1);
            img[pos] = (unsigned short)(p & 0xFFFF);
        }
        __syncthreads();
        for (int i = t; i < ptot; i += 256)
            esrc[S + i] = img[i];
        return;
    }
    // ---- embed GEMM role ----
    int tid = threadIdx.x;
    int wn = tid >> 6;
    int lane = tid & 63;
    int quad = lane >> 4;
    int l15 = lane & 15;
    int row0 = (blockIdx.x - NBUCK) * 32;

    floatx4 acc[2][4];
    #pragma unroll
    for (int mt = 0; mt < 2; mt++)
        #pragma unroll
        for (int n = 0; n < 4; n++)
            acc[mt][n] = (floatx4){0.f, 0.f, 0.f, 0.f};

    int r0 = row0 + l15;
    int r1 = row0 + 16 + l15;
    bool ok0 = r0 < N_NODESC, ok1 = r1 < N_NODESC;
    const float* h0 = h + (size_t)r0 * IN_DIMC + quad * 8;
    const float* h1 = h + (size_t)r1 * IN_DIMC + quad * 8;
    const unsigned short* bp = wsw + ((size_t)(wn * 4) * 64 + lane) * 8;

    #pragma unroll
    for (int ks = 0; ks < 4; ks++) {
        float4 f00 = ok0 ? *(const float4*)(h0 + ks * 32)     : (float4){0,0,0,0};
        float4 f01 = ok0 ? *(const float4*)(h0 + ks * 32 + 4) : (float4){0,0,0,0};
        float4 f10 = ok1 ? *(const float4*)(h1 + ks * 32)     : (float4){0,0,0,0};
        float4 f11 = ok1 ? *(const float4*)(h1 + ks * 32 + 4) : (float4){0,0,0,0};
        short8 afr[2], bfr[4];
        uint4 av;
        av.x = pkb(f00.x, f00.y); av.y = pkb(f00.z, f00.w);
        av.z = pkb(f01.x, f01.y); av.w = pkb(f01.z, f01.w);
        afr[0] = *(short8*)&av;
        av.x = pkb(f10.x, f10.y); av.y = pkb(f10.z, f10.w);
        av.z = pkb(f11.x, f11.y); av.w = pkb(f11.z, f11.w);
        afr[1] = *(short8*)&av;
        const unsigned short* wp = bp + (size_t)ks * 8192;
        #pragma unroll
        for (int n = 0; n < 4; n++)
            bfr[n] = *(const short8*)(wp + n * 512);
        #pragma unroll
        for (int mt = 0; mt < 2; mt++)
            #pragma unroll
            for (int n = 0; n < 4; n++)
                acc[mt][n] = __builtin_amdgcn_mfma_f32_16x16x32_bf16(
                    afr[mt], bfr[n], acc[mt][n], 0, 0, 0);
    }

    float bv[4];
    #pragma unroll
    for (int n = 0; n < 4; n++) bv[n] = bias[wn * 64 + n * 16 + l15];
    #pragma unroll
    for (int mt = 0; mt < 2; mt++) {
        #pragma unroll
        for (int r = 0; r < 4; r++) {
            int row = row0 + mt * 16 + quad * 4 + r;
            #pragma unroll
            for (int n = 0; n < 4; n++) {
                int col = wn * 64 + n * 16 + l15;
                // pad rows (incl. ZROW) written as 0 so gather padding adds nothing
                float v = acc[mt][n][r] + bv[n];
                xq[(size_t)row * HIDC + col] = (row < N_NODESC) ? f2q(v) : (unsigned char)0;
            }
        }
    }
}

// ---------------- per-node mean aggregation: 32 lanes x 8B, vectorized indices ----------------
// R7-verified. Near LLC-BW roofline (205 MB/layer of random 256B rows @ ~7 TB/s).
__global__ __launch_bounds__(256, 8) void k_aggregate(const unsigned char* __restrict__ xq,
        const int* __restrict__ offs, const int* __restrict__ ndeg,
        const unsigned short* __restrict__ esrc, unsigned char* __restrict__ cq) {
    int gidx = blockIdx.x * 256 + threadIdx.x;
    int node = gidx >> 5;                     // grid exact: 6250 blocks * 8 nodes
    int lane = threadIdx.x & 31;
    int beg = offs[node];
    int dn = ndeg[node];
    int pd = (dn + 7) & ~7;
    int end = beg + pd;
    float a[8];
    #pragma unroll
    for (int j = 0; j < 8; j++) a[j] = 0.f;
    size_t loff = (size_t)lane * 8;
    #define ACC8(v) do { \
        floatx2 t0 = __builtin_amdgcn_cvt_pk_f32_fp8((v).x, false); \
        floatx2 t1 = __builtin_amdgcn_cvt_pk_f32_fp8((v).x, true);  \
        floatx2 t2 = __builtin_amdgcn_cvt_pk_f32_fp8((v).y, false); \
        floatx2 t3 = __builtin_amdgcn_cvt_pk_f32_fp8((v).y, true);  \
        a[0] += t0.x; a[1] += t0.y; a[2] += t1.x; a[3] += t1.y;     \
        a[4] += t2.x; a[5] += t2.y; a[6] += t3.x; a[7] += t3.y;     \
    } while (0)
    if (pd > 0) {
        uint4 si = *(const uint4*)&esrc[beg];     // 8 indices, one 16B load
        for (int e = beg; e < end; e += 8) {
            uint4 sn;
            if (e + 8 < end) sn = *(const uint4*)&esrc[e + 8];
            uint2 v[8];
            v[0] = *(const uint2*)(xq + (size_t)(si.x & 0xFFFF) * HIDC + loff);
            v[1] = *(const uint2*)(xq + (size_t)(si.x >> 16)    * HIDC + loff);
            v[2] = *(const uint2*)(xq + (size_t)(si.y & 0xFFFF) * HIDC + loff);
            v[3] = *(const uint2*)(xq + (size_t)(si.y >> 16)    * HIDC + loff);
            v[4] = *(const uint2*)(xq + (size_t)(si.z & 0xFFFF) * HIDC + loff);
            v[5] = *(const uint2*)(xq + (size_t)(si.z >> 16)    * HIDC + loff);
            v[6] = *(const uint2*)(xq + (size_t)(si.w & 0xFFFF) * HIDC + loff);
            v[7] = *(const uint2*)(xq + (size_t)(si.w >> 16)    * HIDC + loff);
            #pragma unroll
            for (int j = 0; j < 8; j++) ACC8(v[j]);
            si = sn;
        }
    }
    #undef ACC8
    float w = 1.0f / (float)max(dn, 1);
    uint2 o;
    o.x = pk4q(a[0] * w, a[1] * w, a[2] * w, a[3] * w);
    o.y = pk4q(a[4] * w, a[5] * w, a[6] * w, a[7] * w);
    *(uint2*)(cq + (size_t)node * HIDC + loff) = o;
}

// ---------------- layer GEMM: 64-row tile, fp8 MFMA, 2-deep weight pipeline ----------------
// 782 blocks; weight L2 loads pipelined TWO K-steps ahead (covers ~2x16-MFMA latency);
// A-frags direct ds_read. LAST: register-reduce rows per graph -> hg atomics.
template<bool LAST>
__global__ __launch_bounds__(256, 4) void k_lgemm(unsigned char* __restrict__ xq,
        const unsigned char* __restrict__ cq, const unsigned char* __restrict__ wq,
        const float* __restrict__ bias, const int* __restrict__ gid,
        float* __restrict__ hg) {
    __shared__ unsigned long long panelA64[2048];  // 16 KB: 64 rows x 256 B
    __shared__ unsigned long long panelC64[2048];  // 16 KB
    __shared__ float rs[64];
    __shared__ signed char ggl[LAST ? 64 : 1];     // per-row local graph index
    __shared__ int g0s;
    unsigned char* panelA = (unsigned char*)panelA64;
    unsigned char* panelC = (unsigned char*)panelC64;
    int tid = threadIdx.x;
    int w = tid >> 6;
    int lane = tid & 63;
    int quad = lane >> 4;
    int l15 = lane & 15;
    int row0 = blockIdx.x * 64;

    // async stage both fp8 panels (wave w covers bytes [w*4096, w*4096+4096) of each)
    {
        #pragma unroll
        for (int i = 0; i < 4; i++) {
            int ldsoff = w * 4096 + i * 1024 + lane * 16;
            int r = ldsoff >> 8;                  // row 0..63 (256 B/row)
            int ch = (ldsoff & 255) >> 4;         // physical 16B chunk 0..15
            int lc = ch ^ (r & 15);               // logical chunk (XOR swizzle)
            ldscp16(xq + (size_t)(row0 + r) * HIDC + lc * 16, &panelA[w * 4096 + i * 1024]);
            ldscp16(cq + (size_t)(row0 + r) * HIDC + lc * 16, &panelC[w * 4096 + i * 1024]);
        }
    }
    __syncthreads();   // vmcnt drained -> both panels visible

    floatx4 acc[4][4];
    #pragma unroll
    for (int mt = 0; mt < 4; mt++)
        #pragma unroll
        for (int n = 0; n < 4; n++)
            acc[mt][n] = (floatx4){0.f, 0.f, 0.f, 0.f};

    const unsigned char* bp = wq + ((size_t)(w * 4) * 64 + lane) * 8;  // bytes; step stride 8192

    // weights pipelined two K-steps ahead (L2-latency cover); A-frags direct ds_read
    long long b0[4], b1[4], b2[4];
    #pragma unroll
    for (int n = 0; n < 4; n++) b0[n] = *(const long long*)(bp + n * 512);
    #pragma unroll
    for (int n = 0; n < 4; n++) b1[n] = *(const long long*)(bp + 8192 + n * 512);

    #pragma unroll
    for (int st = 0; st < 16; st++) {
        if (st < 14) {
            const unsigned char* wp = bp + (size_t)(st + 2) * 8192;
            #pragma unroll
            for (int n = 0; n < 4; n++)
                b2[n] = *(const long long*)(wp + n * 512);
        }
        const unsigned char* pan = (st < 8) ? panelA : panelC;
        int ks = st & 7;
        long long afr[4];
        #pragma unroll
        for (int mt = 0; mt < 4; mt++) {
            int row = mt * 16 + l15;
            int lc = ks * 2 + (quad >> 1);
            int phys = lc ^ (row & 15);
            afr[mt] = *(const long long*)&pan[row * 256 + phys * 16 + (quad & 1) * 8];
        }
        #pragma unroll
        for (int mt = 0; mt < 4; mt++)
            #pragma unroll
            for (int n = 0; n < 4; n++)
                acc[mt][n] = __builtin_amdgcn_mfma_f32_16x16x32_fp8_fp8(
                    afr[mt], b0[n], acc[mt][n], 0, 0, 0);
        #pragma unroll
        for (int n = 0; n < 4; n++) { b0[n] = b1[n]; b1[n] = b2[n]; }
    }

    float bv[4];
    #pragma unroll
    for (int n = 0; n < 4; n++) bv[n] = bias[w * 64 + n * 16 + l15];
    #pragma unroll
    for (int mt = 0; mt < 4; mt++)
        #pragma unroll
        for (int n = 0; n < 4; n++)
            #pragma unroll
            for (int r = 0; r < 4; r++)
                acc[mt][n][r] += bv[n];

    // row L2-norm across 4 col-waves
    __syncthreads();
    if (tid < 64) rs[tid] = 0.f;
    if constexpr (LAST) {
        if (tid < 64) {
            int g0 = gid[min(row0, N_NODESC - 1)];
            int gv = gid[min(row0 + tid, N_NODESC - 1)] - g0;
            ggl[tid] = (signed char)min(gv, 3);
            if (tid == 0) g0s = g0;
        }
    }
    __syncthreads();
    #pragma unroll
    for (int mt = 0; mt < 4; mt++) {
        #pragma unroll
        for (int r = 0; r < 4; r++) {
            float p = acc[mt][0][r] * acc[mt][0][r] + acc[mt][1][r] * acc[mt][1][r]
                    + acc[mt][2][r] * acc[mt][2][r] + acc[mt][3][r] * acc[mt][3][r];
            p += __shfl_xor(p, 1);
            p += __shfl_xor(p, 2);
            p += __shfl_xor(p, 4);
            p += __shfl_xor(p, 8);
            if (l15 == 0) atomicAdd(&rs[mt * 16 + quad * 4 + r], p);
        }
    }
    __syncthreads();

    // epilogue: normalize + relu + residual. LAST keeps nv in acc for pooling.
    #pragma unroll
    for (int mt = 0; mt < 4; mt++) {
        #pragma unroll
        for (int r = 0; r < 4; r++) {
            int lrow = mt * 16 + quad * 4 + r;
            int row = row0 + lrow;
            float inv = 1.0f / fmaxf(sqrtf(rs[lrow]), EPSV);
            #pragma unroll
            for (int n = 0; n < 4; n++) {
                // residual base: fp8 x_old from panelA (same value the GEMM used)
                int phys = (w * 4 + n) ^ (lrow & 15);
                float xo = q2f((unsigned)panelA[lrow * 256 + phys * 16 + l15]);
                float nv = xo + fmaxf(acc[mt][n][r] * inv, 0.f);
                if constexpr (LAST) {
                    acc[mt][n][r] = nv;
                } else if (row < N_NODESC) {
                    int col = w * 64 + n * 16 + l15;
                    xq[(size_t)row * HIDC + col] = f2q(nv);
                }
            }
        }
    }
    if constexpr (LAST) {
        // per-graph register reduction over this thread's 16 rows, then shfl
        // across the 4 quads sharing each column, then 1 atomic per column.
        int nspan = (int)ggl[63] + 1;
        int g0 = g0s;
        for (int gl = 0; gl < nspan; gl++) {
            float s[4] = {0.f, 0.f, 0.f, 0.f};
            #pragma unroll
            for (int mt = 0; mt < 4; mt++) {
                #pragma unroll
                for (int r = 0; r < 4; r++) {
                    int lrow = mt * 16 + quad * 4 + r;
                    bool m = ((int)ggl[lrow] == gl) && (row0 + lrow < N_NODESC);
                    float f = m ? 1.f : 0.f;
                    #pragma unroll
                    for (int n = 0; n < 4; n++) s[n] += f * acc[mt][n][r];
                }
            }
            #pragma unroll
            for (int n = 0; n < 4; n++) {
                s[n] += __shfl_xor(s[n], 16);
                s[n] += __shfl_xor(s[n], 32);
            }
            if (quad == 0) {
                #pragma unroll
                for (int n = 0; n < 4; n++)
                    atomicAdd(&hg[(g0 + gl) * HIDC + w * 64 + n * 16 + l15], s[n]);
            }
        }
    }
}

// ---------------- readout: per-wave shfl reduce, single barrier ----------------
__global__ __launch_bounds__(256) void k_readout(const float* __restrict__ hg,
        const int* __restrict__ gstart, const float* __restrict__ ppos,
        const float* __restrict__ pneg, const float* __restrict__ wfc,
        float* __restrict__ out) {
    __shared__ float part[10][4];
    int t = threadIdx.x;
    int g = blockIdx.x;
    int wv = t >> 6;
    int ln = t & 63;
    int beg = gstart[g], end = gstart[g + 1];
    float inv = 1.0f / (float)max(end - beg, 1);
    float hgv = hg[g * HIDC + t] * inv;
    #pragma unroll
    for (int p = 0; p < 10; p++) {
        const float* P = (p < 5) ? (ppos + p * HIDC) : (pneg + (p - 5) * HIDC);
        float d = hgv - P[t];
        float sq = d * d;
        sq += __shfl_xor(sq, 1);
        sq += __shfl_xor(sq, 2);
        sq += __shfl_xor(sq, 4);
        sq += __shfl_xor(sq, 8);
        sq += __shfl_xor(sq, 16);
        sq += __shfl_xor(sq, 32);
        if (ln == 0) part[p][wv] = sq;
    }
    __syncthreads();
    if (t == 0) {
        float y = 0.f;
        #pragma unroll
        for (int p = 0; p < 10; p++) {
            float dd = part[p][0] + part[p][1] + part[p][2] + part[p][3];
            y += logf((dd + 1.0f) / (dd + EPSV)) * wfc[p];
        }
        out[g] = 1.0f / (1.0f + expf(-y));
    }
}

extern "C" void kernel_launch(void* const* d_in, const int* in_sizes, int n_in,
                              void* d_out, int out_size, void* d_ws, size_t ws_size,
                              hipStream_t stream) {
    const float* h    = (const float*)d_in[0];
    const int*   src  = (const int*)d_in[1];
    const int*   dst  = (const int*)d_in[2];
    const int*   gid  = (const int*)d_in[3];
    const float* Wemb = (const float*)d_in[4];
    const float* bemb = (const float*)d_in[5];
    const float* Ws   = (const float*)d_in[6];
    const float* bs   = (const float*)d_in[7];
    const float* ppos = (const float*)d_in[8];
    const float* pneg = (const float*)d_in[9];
    const float* wfc  = (const float*)d_in[10];
    float* out = (float*)d_out;

    char* ws = (char*)d_ws;
    size_t off = 0;
    auto alloc = [&](size_t bytes) {
        void* p = ws + off;
        off += (bytes + 255) & ~(size_t)255;
        return p;
    };
    unsigned char*  xq     = (unsigned char*)alloc((size_t)NPAD * HIDC);       // fp8 activation (in-place)
    unsigned char*  cq     = (unsigned char*)alloc((size_t)NPAD * HIDC);       // fp8 aggregate out
    unsigned short* wsw    = (unsigned short*)alloc((size_t)(IN_DIMC * HIDC) * 2);          // bf16 embed W
    unsigned char*  wq     = (unsigned char*)alloc((size_t)(N_LAYERSC * 2 * HIDC * HIDC)); // fp8 layer W
    int*            offs   = (int*)alloc((size_t)(N_NODESC + 1) * 4);
    int*            ndeg   = (int*)alloc((size_t)N_NODESC * 4);
    unsigned short* esrc   = (unsigned short*)alloc((size_t)NBUCK * PBUCK * 2);  // padded slabs
    unsigned*       ebpack = (unsigned*)alloc((size_t)NBUCK * ESLAB * 4);        // fixed slabs
    int*            gcurB  = (int*)alloc((size_t)NBUCK * 4);
    int*            gstart = (int*)alloc((size_t)(N_GRAPHSC + 1) * 4);
    float*          hg     = (float*)alloc((size_t)N_GRAPHSC * HIDC * 4);
    (void)ws_size; (void)in_sizes; (void)n_in; (void)out_size;

    hipMemsetAsync(gcurB, 0, (size_t)NBUCK * 4, stream);
    hipMemsetAsync(hg, 0, (size_t)N_GRAPHSC * HIDC * 4, stream);

    const int LYR = 2 * HIDC * HIDC;
    // wconv | gbounds | scatter+count (all independent)
    k_pre1<<<WCONV_BLKS + 1 + NBLK1, 256, 0, stream>>>(Wemb, Ws, wsw, wq, gid, gstart, src, dst, gcurB, ebpack);
    // bbuild | embed GEMM (both depend only on K1; mutually independent)
    k_build_egemm<<<NBUCK + NPAD / 32, 256, 0, stream>>>(ebpack, gcurB, offs, ndeg, esrc, h, wsw, bemb, xq);

    for (int l = 0; l < N_LAYERSC; l++) {
        k_aggregate<<<(N_NODESC * 32) / 256, 256, 0, stream>>>(xq, offs, ndeg, esrc, cq);
        if (l < N_LAYERSC - 1)
            k_lgemm<false><<<NPAD / 64, 256, 0, stream>>>(
                xq, cq, wq + (size_t)l * LYR, bs + (size_t)l * HIDC, gid, hg);
        else
            k_lgemm<true><<<NPAD / 64, 256, 0, stream>>>(
                xq, cq, wq + (size_t)l * LYR, bs + (size_t)l * HIDC, gid, hg);
    }
    k_readout<<<N_GRAPHSC, 256, 0, stream>>>(hg, gstart, ppos, pneg, wfc, out);
}